// Round 4
// baseline (84.573 us; speedup 1.0000x reference)
//
#include <hip/hip_runtime.h>

typedef __attribute__((ext_vector_type(4))) float f32x4;
typedef __attribute__((ext_vector_type(4))) float float4v;
typedef __attribute__((ext_vector_type(8))) short bf16x8;
typedef __attribute__((ext_vector_type(8))) unsigned short ushort8;

#define DEVI static __device__ __forceinline__

namespace {
constexpr int kL = 2048, kS = 2048, kH = 8;
constexpr int QB = 64, KVB = 64, NKT = kS / KVB;
constexpr float kC = 0.18033688f;        // (1/8) * log2(e), folded into Q
constexpr float kEpsC = 3.252139e-10f;   // kC^2 * 1e-8
constexpr int KTILE = 8448;              // 8192 B data + 256 B kn2 tail
constexpr int VTILE = 8192;
constexpr int KBH = 32 * KTILE;
constexpr int VBH = 32 * VTILE;
}

// XOR swizzle on flat byte offset for [rows][64] bf16 tiles (128B row stride).
DEVI int swz(int byteoff) { return byteoff ^ (((byteoff >> 7) & 7) << 4); }

DEVI unsigned cvtpk(float lo, float hi) {
  unsigned r;
  asm("v_cvt_pk_bf16_f32 %0, %1, %2" : "=v"(r) : "v"(lo), "v"(hi));
  return r;
}

// ---------- prepass 1: K -> tiled, PRE-SWIZZLED bf16 tiles + kn2 tail ----------
__global__ __launch_bounds__(256) void prep_k(const float* __restrict__ Kg,
                                              char* __restrict__ Kb) {
  const int chunk = (int)blockIdx.x * 256 + (int)threadIdx.x;  // one 16B chunk
  const int tile = chunk >> 9;
  const int i = chunk & 511;
  const int bh = tile >> 5, kt = tile & 31;
  const int b = bh >> 3, h = bh & 7;
  const int row = i >> 3;
  const int colsel = (i & 7) ^ (row & 7);     // swz on chunk index
  const int s = kt * 64 + row;
  const float* src = Kg + (((size_t)b * kS + s) * kH + h) * 64 + colsel * 8;
  float4v v0 = *(const float4v*)(src);
  float4v v1 = *(const float4v*)(src + 4);
  float pn = v0.x*v0.x + v0.y*v0.y + v0.z*v0.z + v0.w*v0.w
           + v1.x*v1.x + v1.y*v1.y + v1.z*v1.z + v1.w*v1.w;
  union { unsigned w[4]; ushort8 u; } o;
  o.w[0] = cvtpk(v0.x, v0.y); o.w[1] = cvtpk(v0.z, v0.w);
  o.w[2] = cvtpk(v1.x, v1.y); o.w[3] = cvtpk(v1.z, v1.w);
  char* tb = Kb + (size_t)tile * KTILE;
  *(ushort8*)(tb + i * 16) = o.u;
  pn += __shfl_xor(pn, 1);
  pn += __shfl_xor(pn, 2);
  pn += __shfl_xor(pn, 4);
  if ((i & 7) == 0) *(float*)(tb + 8192 + row * 4) = pn;  // exact f32 |k|^2
}

// ---------- prepass 2: V -> tiled, sigma-permuted, PRE-SWIZZLED bf16 ----------
__global__ __launch_bounds__(256) void prep_v(const float* __restrict__ Vg,
                                              char* __restrict__ Vt) {
  __shared__ char tile[64 * 128];  // [s][d] bf16, swizzled
  const int t = (int)threadIdx.x;
  const int bid = (int)blockIdx.x;
  const int st = bid & 31, bh = bid >> 5;
  const int b = bh >> 3, h = bh & 7;
  {
    const int sl = t >> 2, c0 = (t & 3) * 16;
    const float* src = Vg + (((size_t)b * kS + st * 64 + sl) * kH + h) * 64 + c0;
    float4v v0 = *(const float4v*)(src);
    float4v v1 = *(const float4v*)(src + 4);
    float4v v2 = *(const float4v*)(src + 8);
    float4v v3 = *(const float4v*)(src + 12);
    union { unsigned w[4]; ushort8 u; } t0, t1;
    t0.w[0] = cvtpk(v0.x, v0.y); t0.w[1] = cvtpk(v0.z, v0.w);
    t0.w[2] = cvtpk(v1.x, v1.y); t0.w[3] = cvtpk(v1.z, v1.w);
    t1.w[0] = cvtpk(v2.x, v2.y); t1.w[1] = cvtpk(v2.z, v2.w);
    t1.w[2] = cvtpk(v3.x, v3.y); t1.w[3] = cvtpk(v3.z, v3.w);
    *(ushort8*)(tile + swz(sl * 128 + c0 * 2)) = t0.u;
    *(ushort8*)(tile + swz(sl * 128 + c0 * 2 + 16)) = t1.u;
  }
  __syncthreads();
  char* dst = Vt + (size_t)bid * VTILE;
#pragma unroll
  for (int cc = 0; cc < 2; ++cc) {
    const int i = t * 2 + cc;
    const int z = swz(i * 16);
    const int d = z >> 7;
    const int k0 = ((z >> 4) & 7) * 8;
    union { unsigned short s[8]; ushort8 u; } o;
#pragma unroll
    for (int j = 0; j < 8; ++j) {
      const int k = k0 + j;
      const int sig = (((k >> 5) * 2 + ((k & 7) >> 2)) << 4) |
                      (((k >> 3) & 3) << 2) | (k & 3);
      o.s[j] = *(const unsigned short*)(tile + swz(sig * 128 + d * 2));
    }
    *(ushort8*)(dst + i * 16) = o.u;
  }
}

// ---------- main attention kernel (1-deep software pipeline) ----------
__global__ __launch_bounds__(256) void geo_attn_kernel(
    const float* __restrict__ Qg, const char* __restrict__ Kb,
    const char* __restrict__ Vt, float* __restrict__ Og) {
  __shared__ char kbuf[2][8192];   // K ring (read kt, stage kt+1)
  __shared__ char vbuf[3][8192];   // V ring (read kt-1, idle kt, stage kt+1)

  const int t = (int)threadIdx.x;
  const int wv = t >> 6, lane = t & 63, gg = lane >> 4, cl = lane & 15;
  const int bh = (int)blockIdx.y, b = bh >> 3, h = bh & 7;
  const int l0 = (int)blockIdx.x * QB;

  // ---- Q fragment straight from global, scaled by kC; exact f32 |q|^2 ----
  const int q = l0 + wv * 16 + cl;
  const float* qp = Qg + (((size_t)b * kL + q) * kH + h) * 64;
  float4v x0 = *(const float4v*)(qp + gg * 8);
  float4v x1 = *(const float4v*)(qp + gg * 8 + 4);
  float4v x2 = *(const float4v*)(qp + gg * 8 + 32);
  float4v x3 = *(const float4v*)(qp + gg * 8 + 36);
  x0 *= kC; x1 *= kC; x2 *= kC; x3 *= kC;
  float pn = 0.f;
#pragma unroll
  for (int j = 0; j < 4; ++j) {
    pn = fmaf(x0[j], x0[j], pn); pn = fmaf(x1[j], x1[j], pn);
    pn = fmaf(x2[j], x2[j], pn); pn = fmaf(x3[j], x3[j], pn);
  }
  union frag { bf16x8 v; unsigned w[4]; };
  frag qb0, qb1;
  qb0.w[0] = cvtpk(x0.x, x0.y); qb0.w[1] = cvtpk(x0.z, x0.w);
  qb0.w[2] = cvtpk(x1.x, x1.y); qb0.w[3] = cvtpk(x1.z, x1.w);
  qb1.w[0] = cvtpk(x2.x, x2.y); qb1.w[1] = cvtpk(x2.z, x2.w);
  qb1.w[2] = cvtpk(x3.x, x3.y); qb1.w[3] = cvtpk(x3.z, x3.w);
  pn += __shfl_xor(pn, 16);
  pn += __shfl_xor(pn, 32);
  const float qn2 = pn;  // kC^2 * |q|^2 (full row)

  // ---- staging: waves 0-1 own K (4KB each), waves 2-3 own V ----
  const bool isK = (wv < 2);
  const char* gp = (isK ? Kb + (size_t)bh * KBH : Vt + (size_t)bh * VBH)
                   + (wv & 1) * 4096 + lane * 16;
  const int gstride = isK ? KTILE : VTILE;
  const char* ktail = Kb + (size_t)bh * KBH + 8192;

#define STAGE(DSTBASE) do { \
    char* _lb = (DSTBASE) + (wv & 1) * 4096; \
    __builtin_amdgcn_global_load_lds((__attribute__((address_space(1))) void*)(gp),        (__attribute__((address_space(3))) void*)(_lb),        16, 0, 0); \
    __builtin_amdgcn_global_load_lds((__attribute__((address_space(1))) void*)(gp + 1024), (__attribute__((address_space(3))) void*)(_lb + 1024), 16, 0, 0); \
    __builtin_amdgcn_global_load_lds((__attribute__((address_space(1))) void*)(gp + 2048), (__attribute__((address_space(3))) void*)(_lb + 2048), 16, 0, 0); \
    __builtin_amdgcn_global_load_lds((__attribute__((address_space(1))) void*)(gp + 3072), (__attribute__((address_space(3))) void*)(_lb + 3072), 16, 0, 0); \
  } while (0)

  float lsum = 0.f;
  f32x4 oacc[4];
#pragma unroll
  for (int dt = 0; dt < 4; ++dt) oacc[dt] = (f32x4){0.f, 0.f, 0.f, 0.f};

  // prologue: stage tile 0 (K -> kbuf[0], V -> vbuf[0])
  STAGE(isK ? kbuf[0] : vbuf[0]);
  gp += gstride;
  __syncthreads();

  char* kr = kbuf[0]; char* kst = kbuf[1];
  char* vr = vbuf[2]; char* vm = vbuf[0]; char* vst = vbuf[1];
  frag pa0, pa1;
  pa0.w[0] = pa0.w[1] = pa0.w[2] = pa0.w[3] = 0u;
  pa1.w[0] = pa1.w[1] = pa1.w[2] = pa1.w[3] = 0u;

  for (int kt = 0; kt < NKT; ++kt) {
    if (kt + 1 < NKT) {  // stage K(kt+1)->kst, V(kt+1)->vst
      STAGE(isK ? kst : vst);
      gp += gstride;
    }

    // kn2 for this tile (issue early; consumed by scores much later)
    float4v kn2v[4];
#pragma unroll
    for (int nt = 0; nt < 4; ++nt)
      kn2v[nt] = *(const float4v*)(ktail + nt * 64 + gg * 16);
    ktail += KTILE;
    float qk2[4][4];
#pragma unroll
    for (int nt = 0; nt < 4; ++nt)
#pragma unroll
      for (int r = 0; r < 4; ++r) qk2[nt][r] = qn2 * kn2v[nt][r];

    // ---- QK^T(kt): issue MFMAs; results consumed after PV block ----
    f32x4 dacc[4];
#pragma unroll
    for (int nt = 0; nt < 4; ++nt) {
      bf16x8 ka0 = *(const bf16x8*)(kr + swz((nt * 16 + cl) * 128 + gg * 16));
      bf16x8 ka1 = *(const bf16x8*)(kr + swz((nt * 16 + cl) * 128 + gg * 16 + 64));
      f32x4 acc = {0.f, 0.f, 0.f, 0.f};
      acc = __builtin_amdgcn_mfma_f32_16x16x32_bf16(ka0, qb0.v, acc, 0, 0, 0);
      acc = __builtin_amdgcn_mfma_f32_16x16x32_bf16(ka1, qb1.v, acc, 0, 0, 0);
      dacc[nt] = acc;
    }

    // ---- PV(kt-1): pure accumulate, hides QK^T latency ----
    if (kt > 0) {
#pragma unroll
      for (int dt = 0; dt < 4; ++dt) {
        bf16x8 vb0 = *(const bf16x8*)(vr + swz((dt * 16 + cl) * 128 + gg * 16));
        bf16x8 vb1 = *(const bf16x8*)(vr + swz((dt * 16 + cl) * 128 + gg * 16 + 64));
        f32x4 acc = oacc[dt];
        acc = __builtin_amdgcn_mfma_f32_16x16x32_bf16(pa0.v, vb0, acc, 0, 0, 0);
        acc = __builtin_amdgcn_mfma_f32_16x16x32_bf16(pa1.v, vb1, acc, 0, 0, 0);
        oacc[dt] = acc;
      }
    }

    // ---- scores(kt): p = 2^sqrt(max(qn2*kn2 - dot^2, eps)) (trans pipe) ----
    float sc[4][4];
#pragma unroll
    for (int nt = 0; nt < 4; ++nt)
#pragma unroll
      for (int r = 0; r < 4; ++r) {
        const float dot = dacc[nt][r];
        float w2 = fmaf(-dot, dot, qk2[nt][r]);
        w2 = fmaxf(w2, kEpsC);
        const float p = __builtin_amdgcn_exp2f(__builtin_amdgcn_sqrtf(w2));
        sc[nt][r] = p;
        lsum += p;
      }

    // ---- pack pa(kt) for next iteration's PV ----
    pa0.w[0] = cvtpk(sc[0][0], sc[0][1]); pa0.w[1] = cvtpk(sc[0][2], sc[0][3]);
    pa0.w[2] = cvtpk(sc[1][0], sc[1][1]); pa0.w[3] = cvtpk(sc[1][2], sc[1][3]);
    pa1.w[0] = cvtpk(sc[2][0], sc[2][1]); pa1.w[1] = cvtpk(sc[2][2], sc[2][3]);
    pa1.w[2] = cvtpk(sc[3][0], sc[3][1]); pa1.w[3] = cvtpk(sc[3][2], sc[3][3]);

    __syncthreads();  // stage(kt+1) drained; all reads of kr/vr done
    { char* tmp = kr; kr = kst; kst = tmp; }
    { char* tmp = vr; vr = vm; vm = vst; vst = tmp; }
  }
#undef STAGE

  // ---- drain pipeline: PV(NKT-1) ----
#pragma unroll
  for (int dt = 0; dt < 4; ++dt) {
    bf16x8 vb0 = *(const bf16x8*)(vr + swz((dt * 16 + cl) * 128 + gg * 16));
    bf16x8 vb1 = *(const bf16x8*)(vr + swz((dt * 16 + cl) * 128 + gg * 16 + 64));
    f32x4 acc = oacc[dt];
    acc = __builtin_amdgcn_mfma_f32_16x16x32_bf16(pa0.v, vb0, acc, 0, 0, 0);
    acc = __builtin_amdgcn_mfma_f32_16x16x32_bf16(pa1.v, vb1, acc, 0, 0, 0);
    oacc[dt] = acc;
  }

  // ---- epilogue: deferred lsum reduce across gg, then normalize & store ----
  lsum += __shfl_xor(lsum, 16);
  lsum += __shfl_xor(lsum, 32);
  const float inv = 1.f / lsum;
  float inv4[4];
#pragma unroll
  for (int r = 0; r < 4; ++r)
    inv4[r] = __shfl(inv, (lane & 48) | (gg * 4 + r));
#pragma unroll
  for (int r = 0; r < 4; ++r) {
    const int l = l0 + wv * 16 + gg * 4 + r;
    float* op = Og + (((size_t)b * kL + l) * kH + h) * 64;
#pragma unroll
    for (int dt = 0; dt < 4; ++dt)
      op[dt * 16 + cl] = oacc[dt][r] * inv4[r];
  }
}

extern "C" void kernel_launch(void* const* d_in, const int* in_sizes, int n_in,
                              void* d_out, int out_size, void* d_ws, size_t ws_size,
                              hipStream_t stream) {
  const float* Qg = (const float*)d_in[0];
  const float* Kg = (const float*)d_in[1];
  const float* Vg = (const float*)d_in[2];
  float* Og = (float*)d_out;
  // ws: Kb tiled (32bh*32kt*8448B = 8.25MB) | Vt tiled (8MB) -> 16.25MB total
  char* Kb = (char*)d_ws;
  char* Vt = (char*)d_ws + (size_t)1024 * KTILE;
  prep_k<<<2048, 256, 0, stream>>>(Kg, Kb);
  prep_v<<<1024, 256, 0, stream>>>(Vg, Vt);
  dim3 grid(kL / QB, 32);
  geo_attn_kernel<<<grid, dim3(256), 0, stream>>>(Qg, Kb, Vt, Og);
}

// Round 5
// 74.660 us; speedup vs baseline: 1.1328x; 1.1328x over previous
//
#include <hip/hip_runtime.h>

typedef __attribute__((ext_vector_type(2))) float f32x2;
typedef __attribute__((ext_vector_type(4))) float f32x4;
typedef __attribute__((ext_vector_type(4))) float float4v;
typedef __attribute__((ext_vector_type(8))) short bf16x8;
typedef __attribute__((ext_vector_type(8))) unsigned short ushort8;

#define DEVI static __device__ __forceinline__

namespace {
constexpr int kL = 2048, kS = 2048, kH = 8;
constexpr int QB = 64, KVB = 64, NKT = kS / KVB;
constexpr float kC = 0.18033688f;        // (1/8) * log2(e), folded into Q
constexpr int KTILE = 8448;              // 8192 B data + 256 B kn2 tail
constexpr int VTILE = 8192;
constexpr int KBH = 32 * KTILE;
constexpr int VBH = 32 * VTILE;
}

// XOR swizzle on flat byte offset for [rows][64] bf16 tiles (128B row stride).
DEVI int swz(int byteoff) { return byteoff ^ (((byteoff >> 7) & 7) << 4); }

DEVI unsigned cvtpk(float lo, float hi) {
  unsigned r;
  asm("v_cvt_pk_bf16_f32 %0, %1, %2" : "=v"(r) : "v"(lo), "v"(hi));
  return r;
}

// ---------- prepass 1: K -> tiled, PRE-SWIZZLED bf16 tiles + kn2 tail ----------
__global__ __launch_bounds__(256) void prep_k(const float* __restrict__ Kg,
                                              char* __restrict__ Kb) {
  const int chunk = (int)blockIdx.x * 256 + (int)threadIdx.x;  // one 16B chunk
  const int tile = chunk >> 9;
  const int i = chunk & 511;
  const int bh = tile >> 5, kt = tile & 31;
  const int b = bh >> 3, h = bh & 7;
  const int row = i >> 3;
  const int colsel = (i & 7) ^ (row & 7);     // swz on chunk index
  const int s = kt * 64 + row;
  const float* src = Kg + (((size_t)b * kS + s) * kH + h) * 64 + colsel * 8;
  float4v v0 = *(const float4v*)(src);
  float4v v1 = *(const float4v*)(src + 4);
  float pn = v0.x*v0.x + v0.y*v0.y + v0.z*v0.z + v0.w*v0.w
           + v1.x*v1.x + v1.y*v1.y + v1.z*v1.z + v1.w*v1.w;
  union { unsigned w[4]; ushort8 u; } o;
  o.w[0] = cvtpk(v0.x, v0.y); o.w[1] = cvtpk(v0.z, v0.w);
  o.w[2] = cvtpk(v1.x, v1.y); o.w[3] = cvtpk(v1.z, v1.w);
  char* tb = Kb + (size_t)tile * KTILE;
  *(ushort8*)(tb + i * 16) = o.u;
  pn += __shfl_xor(pn, 1);
  pn += __shfl_xor(pn, 2);
  pn += __shfl_xor(pn, 4);
  if ((i & 7) == 0) *(float*)(tb + 8192 + row * 4) = pn;  // exact f32 |k|^2
}

// ---------- prepass 2: V -> tiled, sigma-permuted, PRE-SWIZZLED bf16 ----------
__global__ __launch_bounds__(256) void prep_v(const float* __restrict__ Vg,
                                              char* __restrict__ Vt) {
  __shared__ char tile[64 * 128];  // [s][d] bf16, swizzled
  const int t = (int)threadIdx.x;
  const int bid = (int)blockIdx.x;
  const int st = bid & 31, bh = bid >> 5;
  const int b = bh >> 3, h = bh & 7;
  {
    const int sl = t >> 2, c0 = (t & 3) * 16;
    const float* src = Vg + (((size_t)b * kS + st * 64 + sl) * kH + h) * 64 + c0;
    float4v v0 = *(const float4v*)(src);
    float4v v1 = *(const float4v*)(src + 4);
    float4v v2 = *(const float4v*)(src + 8);
    float4v v3 = *(const float4v*)(src + 12);
    union { unsigned w[4]; ushort8 u; } t0, t1;
    t0.w[0] = cvtpk(v0.x, v0.y); t0.w[1] = cvtpk(v0.z, v0.w);
    t0.w[2] = cvtpk(v1.x, v1.y); t0.w[3] = cvtpk(v1.z, v1.w);
    t1.w[0] = cvtpk(v2.x, v2.y); t1.w[1] = cvtpk(v2.z, v2.w);
    t1.w[2] = cvtpk(v3.x, v3.y); t1.w[3] = cvtpk(v3.z, v3.w);
    *(ushort8*)(tile + swz(sl * 128 + c0 * 2)) = t0.u;
    *(ushort8*)(tile + swz(sl * 128 + c0 * 2 + 16)) = t1.u;
  }
  __syncthreads();
  char* dst = Vt + (size_t)bid * VTILE;
#pragma unroll
  for (int cc = 0; cc < 2; ++cc) {
    const int i = t * 2 + cc;
    const int z = swz(i * 16);
    const int d = z >> 7;
    const int k0 = ((z >> 4) & 7) * 8;
    union { unsigned short s[8]; ushort8 u; } o;
#pragma unroll
    for (int j = 0; j < 8; ++j) {
      const int k = k0 + j;
      const int sig = (((k >> 5) * 2 + ((k & 7) >> 2)) << 4) |
                      (((k >> 3) & 3) << 2) | (k & 3);
      o.s[j] = *(const unsigned short*)(tile + swz(sig * 128 + d * 2));
    }
    *(ushort8*)(dst + i * 16) = o.u;
  }
}

// ---------- main attention kernel ----------
__global__ __launch_bounds__(256, 4) void geo_attn_kernel(
    const float* __restrict__ Qg, const char* __restrict__ Kb,
    const char* __restrict__ Vt, float* __restrict__ Og) {
  __shared__ char lds[2][16384];  // per buf: 8KB K tile | 8KB V tile (linear)

  const int t = (int)threadIdx.x;
  const int wv = t >> 6, lane = t & 63, gg = lane >> 4, cl = lane & 15;
  // XCD-aware decode: blocks n with n&7==c land on XCD c (dispatch round-robin);
  // give each XCD 4 bh values so K/V tiles stay in its private L2.
  const int n = (int)blockIdx.x;
  const int bh = (n & 7) * 4 + ((n >> 3) & 3);
  const int l0 = (n >> 5) * QB;
  const int b = bh >> 3, h = bh & 7;

  // ---- Q fragment straight from global, scaled by kC; exact f32 |q|^2 ----
  const int q = l0 + wv * 16 + cl;
  const float* qp = Qg + (((size_t)b * kL + q) * kH + h) * 64;
  float4v x0 = *(const float4v*)(qp + gg * 8);
  float4v x1 = *(const float4v*)(qp + gg * 8 + 4);
  float4v x2 = *(const float4v*)(qp + gg * 8 + 32);
  float4v x3 = *(const float4v*)(qp + gg * 8 + 36);
  x0 *= kC; x1 *= kC; x2 *= kC; x3 *= kC;
  float pn = 0.f;
#pragma unroll
  for (int j = 0; j < 4; ++j) {
    pn = fmaf(x0[j], x0[j], pn); pn = fmaf(x1[j], x1[j], pn);
    pn = fmaf(x2[j], x2[j], pn); pn = fmaf(x3[j], x3[j], pn);
  }
  union frag { bf16x8 v; unsigned w[4]; };
  frag qb0, qb1;
  qb0.w[0] = cvtpk(x0.x, x0.y); qb0.w[1] = cvtpk(x0.z, x0.w);
  qb0.w[2] = cvtpk(x1.x, x1.y); qb0.w[3] = cvtpk(x1.z, x1.w);
  qb1.w[0] = cvtpk(x2.x, x2.y); qb1.w[1] = cvtpk(x2.z, x2.w);
  qb1.w[2] = cvtpk(x3.x, x3.y); qb1.w[3] = cvtpk(x3.z, x3.w);
  pn += __shfl_xor(pn, 16);
  pn += __shfl_xor(pn, 32);
  const f32x2 qn2p = {pn, pn};  // kC^2 * |q|^2 (full row), packed

  frag vone;  // all-ones bf16 B-fragment for P row-sums on the MFMA pipe
  vone.w[0] = vone.w[1] = vone.w[2] = vone.w[3] = 0x3F803F80u;

  // ---- staging: waves 0-1 own K (4KB each), waves 2-3 own V ----
  const bool isK = (wv < 2);
  const char* gp = (isK ? Kb + (size_t)bh * KBH : Vt + (size_t)bh * VBH)
                   + (wv & 1) * 4096 + lane * 16;
  const int gstride = isK ? KTILE : VTILE;
  const char* ktail = Kb + (size_t)bh * KBH + 8192;

#define STAGE(BUF) do { \
    char* _lb = lds[BUF] + wv * 4096; \
    __builtin_amdgcn_global_load_lds((__attribute__((address_space(1))) void*)(gp),        (__attribute__((address_space(3))) void*)(_lb),        16, 0, 0); \
    __builtin_amdgcn_global_load_lds((__attribute__((address_space(1))) void*)(gp + 1024), (__attribute__((address_space(3))) void*)(_lb + 1024), 16, 0, 0); \
    __builtin_amdgcn_global_load_lds((__attribute__((address_space(1))) void*)(gp + 2048), (__attribute__((address_space(3))) void*)(_lb + 2048), 16, 0, 0); \
    __builtin_amdgcn_global_load_lds((__attribute__((address_space(1))) void*)(gp + 3072), (__attribute__((address_space(3))) void*)(_lb + 3072), 16, 0, 0); \
  } while (0)

  f32x4 oacc[4];
#pragma unroll
  for (int dt = 0; dt < 4; ++dt) oacc[dt] = (f32x4){0.f, 0.f, 0.f, 0.f};
  f32x4 lacc = (f32x4){0.f, 0.f, 0.f, 0.f};

  // prologue: stage tile 0; preload tile 0's kn2
  STAGE(0);
  gp += gstride;
  float4v kn2r[4];
#pragma unroll
  for (int nt = 0; nt < 4; ++nt)
    kn2r[nt] = *(const float4v*)(ktail + nt * 64 + gg * 16);
  ktail += KTILE;
  __syncthreads();

  int cur = 0;
  for (int kt = 0; kt < NKT; ++kt) {
    if (kt + 1 < NKT) { STAGE(cur ^ 1); gp += gstride; }  // prefetch next tile

    // prefetch next tile's kn2 into regs (consumed next iteration)
    float4v kn2n[4];
#pragma unroll
    for (int nt = 0; nt < 4; ++nt)
      kn2n[nt] = *(const float4v*)(ktail + nt * 64 + gg * 16);
    ktail += KTILE;

    const char* ksc = lds[cur];
    const char* vsc = lds[cur] + 8192;

    // ---- QK^T swapped: dacc[nt][r], s_loc=nt*16+4gg+r, q=16wv+cl ----
    f32x4 dacc[4];
#pragma unroll
    for (int nt = 0; nt < 4; ++nt) {
      bf16x8 ka0 = *(const bf16x8*)(ksc + swz((nt * 16 + cl) * 128 + gg * 16));
      bf16x8 ka1 = *(const bf16x8*)(ksc + swz((nt * 16 + cl) * 128 + gg * 16 + 64));
      f32x4 acc = {0.f, 0.f, 0.f, 0.f};
      acc = __builtin_amdgcn_mfma_f32_16x16x32_bf16(ka0, qb0.v, acc, 0, 0, 0);
      acc = __builtin_amdgcn_mfma_f32_16x16x32_bf16(ka1, qb1.v, acc, 0, 0, 0);
      dacc[nt] = acc;
    }

    // ---- scores, packed-f32 pairs: p = 2^sqrt(|qn2*kn2 - dot^2|) ----
    // (score in [0,~23] -> p in [1,2^23]: no max-subtraction needed; |.| is a
    //  free input modifier and only differs from max(.,eps) when true w2≈0)
    unsigned pw[8];
#pragma unroll
    for (int i = 0; i < 8; ++i) {
      const int nt = i >> 1, hh = (i & 1) * 2;
      const f32x2 d2 = {dacc[nt][hh], dacc[nt][hh + 1]};
      const f32x2 k2 = {kn2r[nt][hh], kn2r[nt][hh + 1]};
      const f32x2 w2 = qn2p * k2 - d2 * d2;   // v_pk_mul + v_pk_fma
      const float p0 = __builtin_amdgcn_exp2f(__builtin_amdgcn_sqrtf(fabsf(w2.x)));
      const float p1 = __builtin_amdgcn_exp2f(__builtin_amdgcn_sqrtf(fabsf(w2.y)));
      pw[i] = cvtpk(p0, p1);
    }
    frag pa0, pa1;
    pa0.w[0] = pw[0]; pa0.w[1] = pw[1]; pa0.w[2] = pw[2]; pa0.w[3] = pw[3];
    pa1.w[0] = pw[4]; pa1.w[1] = pw[5]; pa1.w[2] = pw[6]; pa1.w[3] = pw[7];

    // ---- PV + P row-sum (lsum) on the MFMA pipe ----
#pragma unroll
    for (int dt = 0; dt < 4; ++dt) {
      bf16x8 vb0 = *(const bf16x8*)(vsc + swz((dt * 16 + cl) * 128 + gg * 16));
      bf16x8 vb1 = *(const bf16x8*)(vsc + swz((dt * 16 + cl) * 128 + gg * 16 + 64));
      f32x4 acc = oacc[dt];
      acc = __builtin_amdgcn_mfma_f32_16x16x32_bf16(pa0.v, vb0, acc, 0, 0, 0);
      acc = __builtin_amdgcn_mfma_f32_16x16x32_bf16(pa1.v, vb1, acc, 0, 0, 0);
      oacc[dt] = acc;
    }
    lacc = __builtin_amdgcn_mfma_f32_16x16x32_bf16(pa0.v, vone.v, lacc, 0, 0, 0);
    lacc = __builtin_amdgcn_mfma_f32_16x16x32_bf16(pa1.v, vone.v, lacc, 0, 0, 0);

#pragma unroll
    for (int nt = 0; nt < 4; ++nt) kn2r[nt] = kn2n[nt];

    __syncthreads();  // staged tile drained; buffers safe to swap
    cur ^= 1;
  }
#undef STAGE

  // ---- epilogue: lacc[r] = lsum for q-row 4gg+r (all 16 cols identical) ----
#pragma unroll
  for (int r = 0; r < 4; ++r) {
    const int l = l0 + wv * 16 + gg * 4 + r;
    const float inv = 1.f / lacc[r];
    float* op = Og + (((size_t)b * kL + l) * kH + h) * 64;
#pragma unroll
    for (int dt = 0; dt < 4; ++dt)
      op[dt * 16 + cl] = oacc[dt][r] * inv;
  }
}

extern "C" void kernel_launch(void* const* d_in, const int* in_sizes, int n_in,
                              void* d_out, int out_size, void* d_ws, size_t ws_size,
                              hipStream_t stream) {
  const float* Qg = (const float*)d_in[0];
  const float* Kg = (const float*)d_in[1];
  const float* Vg = (const float*)d_in[2];
  float* Og = (float*)d_out;
  // ws: Kb tiled (32bh*32kt*8448B = 8.25MB) | Vt tiled (8MB) -> 16.25MB total
  char* Kb = (char*)d_ws;
  char* Vt = (char*)d_ws + (size_t)1024 * KTILE;
  prep_k<<<2048, 256, 0, stream>>>(Kg, Kb);
  prep_v<<<1024, 256, 0, stream>>>(Vg, Vt);
  geo_attn_kernel<<<dim3(1024), dim3(256), 0, stream>>>(Qg, Kb, Vt, Og);
}

// Round 6
// 71.002 us; speedup vs baseline: 1.1911x; 1.0515x over previous
//
#include <hip/hip_runtime.h>

typedef __attribute__((ext_vector_type(4))) float f32x4;
typedef __attribute__((ext_vector_type(4))) float float4v;
typedef __attribute__((ext_vector_type(8))) short bf16x8;
typedef __attribute__((ext_vector_type(8))) unsigned short ushort8;

#define DEVI static __device__ __forceinline__

namespace {
constexpr int kL = 2048, kS = 2048, kH = 8;
constexpr int QB = 64, KVB = 64, NKT = kS / KVB;
constexpr float kC = 0.18033688f;        // (1/8) * log2(e), folded into Q
constexpr int KTILE = 8448;              // 8192 B data + 256 B kn2 tail
constexpr int VTILE = 8192;
constexpr int KBH = 32 * KTILE;
constexpr int VBH = 32 * VTILE;
constexpr int LBUF = KTILE + VTILE;      // 16640 B per LDS buffer
}

// XOR swizzle on flat byte offset for [rows][64] bf16 tiles (128B row stride).
DEVI int swz(int byteoff) { return byteoff ^ (((byteoff >> 7) & 7) << 4); }

DEVI unsigned cvtpk(float lo, float hi) {
  unsigned r;
  asm("v_cvt_pk_bf16_f32 %0, %1, %2" : "=v"(r) : "v"(lo), "v"(hi));
  return r;
}

// ---------- prepass 1: K -> tiled, PRE-SWIZZLED bf16 tiles + kn2 tail ----------
__global__ __launch_bounds__(256) void prep_k(const float* __restrict__ Kg,
                                              char* __restrict__ Kb) {
  const int chunk = (int)blockIdx.x * 256 + (int)threadIdx.x;  // one 16B chunk
  const int tile = chunk >> 9;
  const int i = chunk & 511;
  const int bh = tile >> 5, kt = tile & 31;
  const int b = bh >> 3, h = bh & 7;
  const int row = i >> 3;
  const int colsel = (i & 7) ^ (row & 7);     // swz on chunk index
  const int s = kt * 64 + row;
  const float* src = Kg + (((size_t)b * kS + s) * kH + h) * 64 + colsel * 8;
  float4v v0 = *(const float4v*)(src);
  float4v v1 = *(const float4v*)(src + 4);
  float pn = v0.x*v0.x + v0.y*v0.y + v0.z*v0.z + v0.w*v0.w
           + v1.x*v1.x + v1.y*v1.y + v1.z*v1.z + v1.w*v1.w;
  union { unsigned w[4]; ushort8 u; } o;
  o.w[0] = cvtpk(v0.x, v0.y); o.w[1] = cvtpk(v0.z, v0.w);
  o.w[2] = cvtpk(v1.x, v1.y); o.w[3] = cvtpk(v1.z, v1.w);
  char* tb = Kb + (size_t)tile * KTILE;
  *(ushort8*)(tb + i * 16) = o.u;
  pn += __shfl_xor(pn, 1);
  pn += __shfl_xor(pn, 2);
  pn += __shfl_xor(pn, 4);
  if ((i & 7) == 0) *(float*)(tb + 8192 + row * 4) = pn;  // exact f32 |k|^2
}

// ---------- prepass 2: V -> tiled, sigma-permuted, PRE-SWIZZLED bf16 ----------
__global__ __launch_bounds__(256) void prep_v(const float* __restrict__ Vg,
                                              char* __restrict__ Vt) {
  __shared__ char tile[64 * 128];  // [s][d] bf16, swizzled
  const int t = (int)threadIdx.x;
  const int bid = (int)blockIdx.x;
  const int st = bid & 31, bh = bid >> 5;
  const int b = bh >> 3, h = bh & 7;
  {
    const int sl = t >> 2, c0 = (t & 3) * 16;
    const float* src = Vg + (((size_t)b * kS + st * 64 + sl) * kH + h) * 64 + c0;
    float4v v0 = *(const float4v*)(src);
    float4v v1 = *(const float4v*)(src + 4);
    float4v v2 = *(const float4v*)(src + 8);
    float4v v3 = *(const float4v*)(src + 12);
    union { unsigned w[4]; ushort8 u; } t0, t1;
    t0.w[0] = cvtpk(v0.x, v0.y); t0.w[1] = cvtpk(v0.z, v0.w);
    t0.w[2] = cvtpk(v1.x, v1.y); t0.w[3] = cvtpk(v1.z, v1.w);
    t1.w[0] = cvtpk(v2.x, v2.y); t1.w[1] = cvtpk(v2.z, v2.w);
    t1.w[2] = cvtpk(v3.x, v3.y); t1.w[3] = cvtpk(v3.z, v3.w);
    *(ushort8*)(tile + swz(sl * 128 + c0 * 2)) = t0.u;
    *(ushort8*)(tile + swz(sl * 128 + c0 * 2 + 16)) = t1.u;
  }
  __syncthreads();
  char* dst = Vt + (size_t)bid * VTILE;
#pragma unroll
  for (int cc = 0; cc < 2; ++cc) {
    const int i = t * 2 + cc;
    const int z = swz(i * 16);
    const int d = z >> 7;
    const int k0 = ((z >> 4) & 7) * 8;
    union { unsigned short s[8]; ushort8 u; } o;
#pragma unroll
    for (int j = 0; j < 8; ++j) {
      const int k = k0 + j;
      const int sig = (((k >> 5) * 2 + ((k & 7) >> 2)) << 4) |
                      (((k >> 3) & 3) << 2) | (k & 3);
      o.s[j] = *(const unsigned short*)(tile + swz(sig * 128 + d * 2));
    }
    *(ushort8*)(dst + i * 16) = o.u;
  }
}

// ---------- main attention kernel ----------
__global__ __launch_bounds__(256, 4) void geo_attn_kernel(
    const float* __restrict__ Qg, const char* __restrict__ Kb,
    const char* __restrict__ Vt, float* __restrict__ Og) {
  // per buffer: 8448 B K tile (data + kn2 tail) | 8192 B V tile, both linear
  __shared__ char lds[2][LBUF];

  const int t = (int)threadIdx.x;
  const int wv = t >> 6, lane = t & 63, gg = lane >> 4, cl = lane & 15;
  // XCD-aware decode: blocks n with n&7==c land on XCD c (dispatch round-robin);
  // give each XCD 4 bh values so K/V tiles stay in its private L2.
  const int n = (int)blockIdx.x;
  const int bh = (n & 7) * 4 + ((n >> 3) & 3);
  const int l0 = (n >> 5) * QB;
  const int b = bh >> 3, h = bh & 7;

  // ---- Q fragment straight from global, scaled by kC; exact f32 |q|^2 ----
  const int q = l0 + wv * 16 + cl;
  const float* qp = Qg + (((size_t)b * kL + q) * kH + h) * 64;
  float4v x0 = *(const float4v*)(qp + gg * 8);
  float4v x1 = *(const float4v*)(qp + gg * 8 + 4);
  float4v x2 = *(const float4v*)(qp + gg * 8 + 32);
  float4v x3 = *(const float4v*)(qp + gg * 8 + 36);
  x0 *= kC; x1 *= kC; x2 *= kC; x3 *= kC;
  float pn = 0.f;
#pragma unroll
  for (int j = 0; j < 4; ++j) {
    pn = fmaf(x0[j], x0[j], pn); pn = fmaf(x1[j], x1[j], pn);
    pn = fmaf(x2[j], x2[j], pn); pn = fmaf(x3[j], x3[j], pn);
  }
  union frag { bf16x8 v; unsigned w[4]; };
  frag qb0, qb1;
  qb0.w[0] = cvtpk(x0.x, x0.y); qb0.w[1] = cvtpk(x0.z, x0.w);
  qb0.w[2] = cvtpk(x1.x, x1.y); qb0.w[3] = cvtpk(x1.z, x1.w);
  qb1.w[0] = cvtpk(x2.x, x2.y); qb1.w[1] = cvtpk(x2.z, x2.w);
  qb1.w[2] = cvtpk(x3.x, x3.y); qb1.w[3] = cvtpk(x3.z, x3.w);
  pn += __shfl_xor(pn, 16);
  pn += __shfl_xor(pn, 32);
  const float qn2 = pn;  // kC^2 * |q|^2 (full row)

  frag vone;  // all-ones bf16 B-fragment for P row-sums on the MFMA pipe
  vone.w[0] = vone.w[1] = vone.w[2] = vone.w[3] = 0x3F803F80u;

  // ---- staging: waves 0-1 own K (4KB + wave0: 256B kn2 tail), 2-3 own V ----
  const bool isK = (wv < 2);
  const char* gp = (isK ? Kb + (size_t)bh * KBH : Vt + (size_t)bh * VBH)
                   + (wv & 1) * 4096 + lane * 16;
  const int gstride = isK ? KTILE : VTILE;
  const char* gt = Kb + (size_t)bh * KBH + 8192 + lane * 4;  // kn2 tail (wave 0)
  const int ldsoff = isK ? (wv & 1) * 4096 : KTILE + (wv & 1) * 4096;

#define STAGE(BUF) do { \
    char* _lb = lds[BUF] + ldsoff; \
    __builtin_amdgcn_global_load_lds((__attribute__((address_space(1))) void*)(gp),        (__attribute__((address_space(3))) void*)(_lb),        16, 0, 0); \
    __builtin_amdgcn_global_load_lds((__attribute__((address_space(1))) void*)(gp + 1024), (__attribute__((address_space(3))) void*)(_lb + 1024), 16, 0, 0); \
    __builtin_amdgcn_global_load_lds((__attribute__((address_space(1))) void*)(gp + 2048), (__attribute__((address_space(3))) void*)(_lb + 2048), 16, 0, 0); \
    __builtin_amdgcn_global_load_lds((__attribute__((address_space(1))) void*)(gp + 3072), (__attribute__((address_space(3))) void*)(_lb + 3072), 16, 0, 0); \
    if (wv == 0) \
      __builtin_amdgcn_global_load_lds((__attribute__((address_space(1))) void*)(gt), (__attribute__((address_space(3))) void*)(lds[BUF] + 8192 + lane * 4), 4, 0, 0); \
  } while (0)

  f32x4 oacc[4];
#pragma unroll
  for (int dt = 0; dt < 4; ++dt) oacc[dt] = (f32x4){0.f, 0.f, 0.f, 0.f};
  f32x4 lacc = (f32x4){0.f, 0.f, 0.f, 0.f};

  // prologue: stage tile 0
  STAGE(0);
  gp += gstride; gt += KTILE;
  __syncthreads();

  int cur = 0;
  for (int kt = 0; kt < NKT; ++kt) {
    if (kt + 1 < NKT) { STAGE(cur ^ 1); gp += gstride; gt += KTILE; }

    const char* ksc = lds[cur];
    const char* vsc = lds[cur] + KTILE;

    // kn2 for this tile from the staged tail (broadcast reads, conflict-free)
    float4v kn2v[4];
#pragma unroll
    for (int nt = 0; nt < 4; ++nt)
      kn2v[nt] = *(const float4v*)(ksc + 8192 + nt * 64 + gg * 16);

    // ---- QK^T swapped: dacc[nt][r], s_loc=nt*16+4gg+r, q=16wv+cl ----
    f32x4 dacc[4];
    __builtin_amdgcn_s_setprio(1);
#pragma unroll
    for (int nt = 0; nt < 4; ++nt) {
      bf16x8 ka0 = *(const bf16x8*)(ksc + swz((nt * 16 + cl) * 128 + gg * 16));
      bf16x8 ka1 = *(const bf16x8*)(ksc + swz((nt * 16 + cl) * 128 + gg * 16 + 64));
      f32x4 acc = {0.f, 0.f, 0.f, 0.f};
      acc = __builtin_amdgcn_mfma_f32_16x16x32_bf16(ka0, qb0.v, acc, 0, 0, 0);
      acc = __builtin_amdgcn_mfma_f32_16x16x32_bf16(ka1, qb1.v, acc, 0, 0, 0);
      dacc[nt] = acc;
    }
    __builtin_amdgcn_s_setprio(0);

    // V fragments (independent of scores; hide LDS latency under trans)
    bf16x8 vb0[4], vb1[4];
#pragma unroll
    for (int dt = 0; dt < 4; ++dt) {
      vb0[dt] = *(const bf16x8*)(vsc + swz((dt * 16 + cl) * 128 + gg * 16));
      vb1[dt] = *(const bf16x8*)(vsc + swz((dt * 16 + cl) * 128 + gg * 16 + 64));
    }

    // ---- scores nt=0,1: p = 2^sqrt(|qn2*kn2 - dot^2|) (trans pipe) ----
    // (score in [0,~23] -> p in [1,2^23]: no max-subtraction; |.| is a free
    //  input modifier, differs from max(.,eps) only when true w2 ~ 0)
    float sc[4][4];
#pragma unroll
    for (int nt = 0; nt < 2; ++nt)
#pragma unroll
      for (int r = 0; r < 4; ++r) {
        const float d = dacc[nt][r];
        const float w2 = fmaf(-d, d, qn2 * kn2v[nt][r]);
        sc[nt][r] = __builtin_amdgcn_exp2f(__builtin_amdgcn_sqrtf(fabsf(w2)));
      }
    frag pa0;
    pa0.w[0] = cvtpk(sc[0][0], sc[0][1]); pa0.w[1] = cvtpk(sc[0][2], sc[0][3]);
    pa0.w[2] = cvtpk(sc[1][0], sc[1][1]); pa0.w[3] = cvtpk(sc[1][2], sc[1][3]);

    // ---- PV half 1 on MFMA pipe while scores nt=2,3 run on trans pipe ----
    __builtin_amdgcn_s_setprio(1);
#pragma unroll
    for (int dt = 0; dt < 4; ++dt)
      oacc[dt] = __builtin_amdgcn_mfma_f32_16x16x32_bf16(pa0.v, vb0[dt], oacc[dt], 0, 0, 0);
    lacc = __builtin_amdgcn_mfma_f32_16x16x32_bf16(pa0.v, vone.v, lacc, 0, 0, 0);
    __builtin_amdgcn_s_setprio(0);

#pragma unroll
    for (int nt = 2; nt < 4; ++nt)
#pragma unroll
      for (int r = 0; r < 4; ++r) {
        const float d = dacc[nt][r];
        const float w2 = fmaf(-d, d, qn2 * kn2v[nt][r]);
        sc[nt][r] = __builtin_amdgcn_exp2f(__builtin_amdgcn_sqrtf(fabsf(w2)));
      }
    frag pa1;
    pa1.w[0] = cvtpk(sc[2][0], sc[2][1]); pa1.w[1] = cvtpk(sc[2][2], sc[2][3]);
    pa1.w[2] = cvtpk(sc[3][0], sc[3][1]); pa1.w[3] = cvtpk(sc[3][2], sc[3][3]);

    __builtin_amdgcn_s_setprio(1);
#pragma unroll
    for (int dt = 0; dt < 4; ++dt)
      oacc[dt] = __builtin_amdgcn_mfma_f32_16x16x32_bf16(pa1.v, vb1[dt], oacc[dt], 0, 0, 0);
    lacc = __builtin_amdgcn_mfma_f32_16x16x32_bf16(pa1.v, vone.v, lacc, 0, 0, 0);
    __builtin_amdgcn_s_setprio(0);

    __syncthreads();  // staged tile drained; buffers safe to swap
    cur ^= 1;
  }
#undef STAGE

  // ---- epilogue: lacc[r] = lsum for q-row 4gg+r (all 16 cols identical) ----
#pragma unroll
  for (int r = 0; r < 4; ++r) {
    const int l = l0 + wv * 16 + gg * 4 + r;
    const float inv = 1.f / lacc[r];
    float* op = Og + (((size_t)b * kL + l) * kH + h) * 64;
#pragma unroll
    for (int dt = 0; dt < 4; ++dt)
      op[dt * 16 + cl] = oacc[dt][r] * inv;
  }
}

extern "C" void kernel_launch(void* const* d_in, const int* in_sizes, int n_in,
                              void* d_out, int out_size, void* d_ws, size_t ws_size,
                              hipStream_t stream) {
  const float* Qg = (const float*)d_in[0];
  const float* Kg = (const float*)d_in[1];
  const float* Vg = (const float*)d_in[2];
  float* Og = (float*)d_out;
  // ws: Kb tiled (32bh*32kt*8448B = 8.25MB) | Vt tiled (8MB) -> 16.25MB total
  char* Kb = (char*)d_ws;
  char* Vt = (char*)d_ws + (size_t)1024 * KTILE;
  prep_k<<<2048, 256, 0, stream>>>(Kg, Kb);
  prep_v<<<1024, 256, 0, stream>>>(Vg, Vt);
  geo_attn_kernel<<<dim3(1024), dim3(256), 0, stream>>>(Qg, Kb, Vt, Og);
}

// Round 7
// 69.166 us; speedup vs baseline: 1.2228x; 1.0266x over previous
//
#include <hip/hip_runtime.h>

typedef __attribute__((ext_vector_type(4))) float f32x4;
typedef __attribute__((ext_vector_type(4))) float float4v;
typedef __attribute__((ext_vector_type(8))) short bf16x8;
typedef __attribute__((ext_vector_type(8))) unsigned short ushort8;

#define DEVI static __device__ __forceinline__

namespace {
constexpr int kL = 2048, kS = 2048, kH = 8;
constexpr int QB = 64, KVB = 64, NKT = kS / KVB;
constexpr float kC = 0.18033688f;        // (1/8) * log2(e), folded into Q
constexpr int KTILE = 8448;              // 8192 B data + 256 B kn2 tail
constexpr int VTILE = 8192;
constexpr int KBH = 32 * KTILE;
constexpr int VBH = 32 * VTILE;
constexpr int LBUF = KTILE + VTILE;      // 16640 B per LDS buffer
}

// XOR swizzle on flat byte offset for [rows][64] bf16 tiles (128B row stride).
DEVI int swz(int byteoff) { return byteoff ^ (((byteoff >> 7) & 7) << 4); }

DEVI unsigned cvtpk(float lo, float hi) {
  unsigned r;
  asm("v_cvt_pk_bf16_f32 %0, %1, %2" : "=v"(r) : "v"(lo), "v"(hi));
  return r;
}

// ---------- prepass 1: K -> tiled, PRE-SWIZZLED bf16 tiles + kn2 tail ----------
__global__ __launch_bounds__(256) void prep_k(const float* __restrict__ Kg,
                                              char* __restrict__ Kb) {
  const int chunk = (int)blockIdx.x * 256 + (int)threadIdx.x;  // one 16B chunk
  const int tile = chunk >> 9;
  const int i = chunk & 511;
  const int bh = tile >> 5, kt = tile & 31;
  const int b = bh >> 3, h = bh & 7;
  const int row = i >> 3;
  const int colsel = (i & 7) ^ (row & 7);     // swz on chunk index
  const int s = kt * 64 + row;
  const float* src = Kg + (((size_t)b * kS + s) * kH + h) * 64 + colsel * 8;
  float4v v0 = *(const float4v*)(src);
  float4v v1 = *(const float4v*)(src + 4);
  float pn = v0.x*v0.x + v0.y*v0.y + v0.z*v0.z + v0.w*v0.w
           + v1.x*v1.x + v1.y*v1.y + v1.z*v1.z + v1.w*v1.w;
  union { unsigned w[4]; ushort8 u; } o;
  o.w[0] = cvtpk(v0.x, v0.y); o.w[1] = cvtpk(v0.z, v0.w);
  o.w[2] = cvtpk(v1.x, v1.y); o.w[3] = cvtpk(v1.z, v1.w);
  char* tb = Kb + (size_t)tile * KTILE;
  *(ushort8*)(tb + i * 16) = o.u;
  pn += __shfl_xor(pn, 1);
  pn += __shfl_xor(pn, 2);
  pn += __shfl_xor(pn, 4);
  if ((i & 7) == 0) *(float*)(tb + 8192 + row * 4) = pn;  // exact f32 |k|^2
}

// ---------- prepass 2: V -> tiled, sigma-permuted, PRE-SWIZZLED bf16 ----------
__global__ __launch_bounds__(256) void prep_v(const float* __restrict__ Vg,
                                              char* __restrict__ Vt) {
  __shared__ char tile[64 * 128];  // [s][d] bf16, swizzled
  const int t = (int)threadIdx.x;
  const int bid = (int)blockIdx.x;
  const int st = bid & 31, bh = bid >> 5;
  const int b = bh >> 3, h = bh & 7;
  {
    const int sl = t >> 2, c0 = (t & 3) * 16;
    const float* src = Vg + (((size_t)b * kS + st * 64 + sl) * kH + h) * 64 + c0;
    float4v v0 = *(const float4v*)(src);
    float4v v1 = *(const float4v*)(src + 4);
    float4v v2 = *(const float4v*)(src + 8);
    float4v v3 = *(const float4v*)(src + 12);
    union { unsigned w[4]; ushort8 u; } t0, t1;
    t0.w[0] = cvtpk(v0.x, v0.y); t0.w[1] = cvtpk(v0.z, v0.w);
    t0.w[2] = cvtpk(v1.x, v1.y); t0.w[3] = cvtpk(v1.z, v1.w);
    t1.w[0] = cvtpk(v2.x, v2.y); t1.w[1] = cvtpk(v2.z, v2.w);
    t1.w[2] = cvtpk(v3.x, v3.y); t1.w[3] = cvtpk(v3.z, v3.w);
    *(ushort8*)(tile + swz(sl * 128 + c0 * 2)) = t0.u;
    *(ushort8*)(tile + swz(sl * 128 + c0 * 2 + 16)) = t1.u;
  }
  __syncthreads();
  char* dst = Vt + (size_t)bid * VTILE;
#pragma unroll
  for (int cc = 0; cc < 2; ++cc) {
    const int i = t * 2 + cc;
    const int z = swz(i * 16);
    const int d = z >> 7;
    const int k0 = ((z >> 4) & 7) * 8;
    union { unsigned short s[8]; ushort8 u; } o;
#pragma unroll
    for (int j = 0; j < 8; ++j) {
      const int k = k0 + j;
      const int sig = (((k >> 5) * 2 + ((k & 7) >> 2)) << 4) |
                      (((k >> 3) & 3) << 2) | (k & 3);
      o.s[j] = *(const unsigned short*)(tile + swz(sig * 128 + d * 2));
    }
    *(ushort8*)(dst + i * 16) = o.u;
  }
}

// ---------- main attention kernel ----------
__global__ __launch_bounds__(256, 4) void geo_attn_kernel(
    const float* __restrict__ Qg, const char* __restrict__ Kb,
    const char* __restrict__ Vt, float* __restrict__ Og) {
  // two buffers, each: 8448 B K tile (data + kn2 tail) | 8192 B V tile
  __shared__ char lds[2 * LBUF];

  const int t = (int)threadIdx.x;
  const int wv = t >> 6, lane = t & 63, gg = lane >> 4, cl = lane & 15;
  // XCD-aware decode: blocks n with n&7==c land on XCD c (dispatch round-robin);
  // give each XCD 4 bh values so K/V tiles stay in its private L2.
  const int n = (int)blockIdx.x;
  const int bh = (n & 7) * 4 + ((n >> 3) & 3);
  const int l0 = (n >> 5) * QB;
  const int b = bh >> 3, h = bh & 7;

  // ---- Q fragment straight from global, scaled by kC; exact f32 |q|^2 ----
  const int q = l0 + wv * 16 + cl;
  const float* qp = Qg + (((size_t)b * kL + q) * kH + h) * 64;
  float4v x0 = *(const float4v*)(qp + gg * 8);
  float4v x1 = *(const float4v*)(qp + gg * 8 + 4);
  float4v x2 = *(const float4v*)(qp + gg * 8 + 32);
  float4v x3 = *(const float4v*)(qp + gg * 8 + 36);
  x0 *= kC; x1 *= kC; x2 *= kC; x3 *= kC;
  float pn = 0.f;
#pragma unroll
  for (int j = 0; j < 4; ++j) {
    pn = fmaf(x0[j], x0[j], pn); pn = fmaf(x1[j], x1[j], pn);
    pn = fmaf(x2[j], x2[j], pn); pn = fmaf(x3[j], x3[j], pn);
  }
  union frag { bf16x8 v; unsigned w[4]; };
  frag qb0, qb1;
  qb0.w[0] = cvtpk(x0.x, x0.y); qb0.w[1] = cvtpk(x0.z, x0.w);
  qb0.w[2] = cvtpk(x1.x, x1.y); qb0.w[3] = cvtpk(x1.z, x1.w);
  qb1.w[0] = cvtpk(x2.x, x2.y); qb1.w[1] = cvtpk(x2.z, x2.w);
  qb1.w[2] = cvtpk(x3.x, x3.y); qb1.w[3] = cvtpk(x3.z, x3.w);
  pn += __shfl_xor(pn, 16);
  pn += __shfl_xor(pn, 32);
  const float qn2 = pn;  // kC^2 * |q|^2 (full row)

  frag vone;  // all-ones bf16 B-fragment for P row-sums on the MFMA pipe
  vone.w[0] = vone.w[1] = vone.w[2] = vone.w[3] = 0x3F803F80u;

  // ---- per-lane LDS read bases; all reads are base + compile-time offset ----
  // swz(cl*128 + gg*16 (+64) + nt*2048 + REGION) ==
  //   [ (cl*128+gg*16 (+64)) ^ ((cl&7)<<4) ] + nt*2048 + REGION
  // since bits 7..9 of the offset equal cl&7 for every read in a tile.
  const char* pA = lds + ((cl * 128 + gg * 16) ^ ((cl & 7) << 4));
  const char* pB = lds + ((cl * 128 + gg * 16 + 64) ^ ((cl & 7) << 4));
  const char* pT = lds + gg * 16;  // kn2 tail base

  // ---- staging: waves 0-1 own K (4KB + wave0: 256B kn2 tail), 2-3 own V ----
  const bool isK = (wv < 2);
  const char* gp = (isK ? Kb + (size_t)bh * KBH : Vt + (size_t)bh * VBH)
                   + (wv & 1) * 4096 + lane * 16;
  const int gstride = isK ? KTILE : VTILE;
  const char* gt = Kb + (size_t)bh * KBH + 8192 + lane * 4;  // kn2 tail (wave 0)
  const int ldsoff = isK ? (wv & 1) * 4096 : KTILE + (wv & 1) * 4096;
  char* const sd0 = lds + ldsoff;                // stage dest, buffer 0
  char* const sd1 = lds + LBUF + ldsoff;         // stage dest, buffer 1
  char* const st0 = lds + 8192 + lane * 4;       // kn2 dest, buffer 0 (wave 0)
  char* const st1 = lds + LBUF + 8192 + lane * 4;

#define STAGE(SD, ST) do { \
    __builtin_amdgcn_global_load_lds((__attribute__((address_space(1))) void*)(gp),        (__attribute__((address_space(3))) void*)(SD),        16, 0, 0); \
    __builtin_amdgcn_global_load_lds((__attribute__((address_space(1))) void*)(gp + 1024), (__attribute__((address_space(3))) void*)((SD) + 1024), 16, 0, 0); \
    __builtin_amdgcn_global_load_lds((__attribute__((address_space(1))) void*)(gp + 2048), (__attribute__((address_space(3))) void*)((SD) + 2048), 16, 0, 0); \
    __builtin_amdgcn_global_load_lds((__attribute__((address_space(1))) void*)(gp + 3072), (__attribute__((address_space(3))) void*)((SD) + 3072), 16, 0, 0); \
    if (wv == 0) \
      __builtin_amdgcn_global_load_lds((__attribute__((address_space(1))) void*)(gt), (__attribute__((address_space(3))) void*)(ST), 4, 0, 0); \
    gp += gstride; gt += KTILE; \
  } while (0)

  f32x4 oacc[4];
#pragma unroll
  for (int dt = 0; dt < 4; ++dt) oacc[dt] = (f32x4){0.f, 0.f, 0.f, 0.f};
  f32x4 lacc = (f32x4){0.f, 0.f, 0.f, 0.f};

  // One tile body; BO is a compile-time buffer byte-offset (0 or LBUF).
#define BODY(BO) do { \
    float4v kn2v[4]; \
    _Pragma("unroll") for (int nt = 0; nt < 4; ++nt) \
      kn2v[nt] = *(const float4v*)(pT + (BO) + 8192 + nt * 64); \
    f32x4 dacc[4]; \
    __builtin_amdgcn_s_setprio(1); \
    _Pragma("unroll") for (int nt = 0; nt < 4; ++nt) { \
      bf16x8 ka0 = *(const bf16x8*)(pA + (BO) + nt * 2048); \
      bf16x8 ka1 = *(const bf16x8*)(pB + (BO) + nt * 2048); \
      f32x4 acc = {0.f, 0.f, 0.f, 0.f}; \
      acc = __builtin_amdgcn_mfma_f32_16x16x32_bf16(ka0, qb0.v, acc, 0, 0, 0); \
      acc = __builtin_amdgcn_mfma_f32_16x16x32_bf16(ka1, qb1.v, acc, 0, 0, 0); \
      dacc[nt] = acc; } \
    __builtin_amdgcn_s_setprio(0); \
    bf16x8 vb0[4], vb1[4]; \
    _Pragma("unroll") for (int dt = 0; dt < 4; ++dt) { \
      vb0[dt] = *(const bf16x8*)(pA + (BO) + KTILE + dt * 2048); \
      vb1[dt] = *(const bf16x8*)(pB + (BO) + KTILE + dt * 2048); } \
    float sc[4][4]; \
    _Pragma("unroll") for (int nt = 0; nt < 2; ++nt) \
      _Pragma("unroll") for (int r = 0; r < 4; ++r) { \
        const float d = dacc[nt][r]; \
        const float w2 = fmaf(-d, d, qn2 * kn2v[nt][r]); \
        sc[nt][r] = __builtin_amdgcn_exp2f(__builtin_amdgcn_sqrtf(fabsf(w2))); } \
    frag pa0; \
    pa0.w[0] = cvtpk(sc[0][0], sc[0][1]); pa0.w[1] = cvtpk(sc[0][2], sc[0][3]); \
    pa0.w[2] = cvtpk(sc[1][0], sc[1][1]); pa0.w[3] = cvtpk(sc[1][2], sc[1][3]); \
    __builtin_amdgcn_s_setprio(1); \
    _Pragma("unroll") for (int dt = 0; dt < 4; ++dt) \
      oacc[dt] = __builtin_amdgcn_mfma_f32_16x16x32_bf16(pa0.v, vb0[dt], oacc[dt], 0, 0, 0); \
    lacc = __builtin_amdgcn_mfma_f32_16x16x32_bf16(pa0.v, vone.v, lacc, 0, 0, 0); \
    __builtin_amdgcn_s_setprio(0); \
    _Pragma("unroll") for (int nt = 2; nt < 4; ++nt) \
      _Pragma("unroll") for (int r = 0; r < 4; ++r) { \
        const float d = dacc[nt][r]; \
        const float w2 = fmaf(-d, d, qn2 * kn2v[nt][r]); \
        sc[nt][r] = __builtin_amdgcn_exp2f(__builtin_amdgcn_sqrtf(fabsf(w2))); } \
    frag pa1; \
    pa1.w[0] = cvtpk(sc[2][0], sc[2][1]); pa1.w[1] = cvtpk(sc[2][2], sc[2][3]); \
    pa1.w[2] = cvtpk(sc[3][0], sc[3][1]); pa1.w[3] = cvtpk(sc[3][2], sc[3][3]); \
    __builtin_amdgcn_s_setprio(1); \
    _Pragma("unroll") for (int dt = 0; dt < 4; ++dt) \
      oacc[dt] = __builtin_amdgcn_mfma_f32_16x16x32_bf16(pa1.v, vb1[dt], oacc[dt], 0, 0, 0); \
    lacc = __builtin_amdgcn_mfma_f32_16x16x32_bf16(pa1.v, vone.v, lacc, 0, 0, 0); \
    __builtin_amdgcn_s_setprio(0); \
  } while (0)

  // prologue: stage tile 0 into buffer 0
  STAGE(sd0, st0);
  __syncthreads();

  // 16 x 2-tile unrolled main loop: buffer offset is a compile-time constant
#pragma unroll 1
  for (int it = 0; it < NKT / 2; ++it) {
    STAGE(sd1, st1);            // tile 2it+1 -> buffer 1 (always exists)
    BODY(0);                    // compute tile 2it from buffer 0
    __syncthreads();
    if (it + 1 < NKT / 2) STAGE(sd0, st0);  // tile 2it+2 -> buffer 0
    BODY(LBUF);                 // compute tile 2it+1 from buffer 1
    __syncthreads();
  }
#undef STAGE
#undef BODY

  // ---- epilogue: lacc[r] = lsum for q-row 4gg+r (all 16 cols identical) ----
#pragma unroll
  for (int r = 0; r < 4; ++r) {
    const int l = l0 + wv * 16 + gg * 4 + r;
    const float inv = 1.f / lacc[r];
    float* op = Og + (((size_t)b * kL + l) * kH + h) * 64;
#pragma unroll
    for (int dt = 0; dt < 4; ++dt)
      op[dt * 16 + cl] = oacc[dt][r] * inv;
  }
}

extern "C" void kernel_launch(void* const* d_in, const int* in_sizes, int n_in,
                              void* d_out, int out_size, void* d_ws, size_t ws_size,
                              hipStream_t stream) {
  const float* Qg = (const float*)d_in[0];
  const float* Kg = (const float*)d_in[1];
  const float* Vg = (const float*)d_in[2];
  float* Og = (float*)d_out;
  // ws: Kb tiled (32bh*32kt*8448B = 8.25MB) | Vt tiled (8MB) -> 16.25MB total
  char* Kb = (char*)d_ws;
  char* Vt = (char*)d_ws + (size_t)1024 * KTILE;
  prep_k<<<2048, 256, 0, stream>>>(Kg, Kb);
  prep_v<<<1024, 256, 0, stream>>>(Vg, Vt);
  geo_attn_kernel<<<dim3(1024), dim3(256), 0, stream>>>(Qg, Kb, Vt, Og);
}